// Round 5
// baseline (875.131 us; speedup 1.0000x reference)
//
#include <hip/hip_runtime.h>
#include <hip/hip_fp16.h>

// ---------------------------------------------------------------------------
// VQFFN1: out = softmax(rmsnorm(x) @ rmsnorm(w)^T) @ w
//   x: [16384,1024] fp32   w: [4096,1024] fp32   out: [16384,1024] fp32
// fp32 scores; GEMM1 compensated fp16 (xh*wh + xl*wh + xh*wl, K'=3072);
// GEMM2 plain fp16 with split-K=2 + f32 HW atomics.
// R2: XOR-swizzled LDS (bank conflicts 3.8e7 -> 0).
// R4: true LDS double-buffering in both GEMMs: prefetch tile t+1 via
//     global_load_lds while computing tile t; raw s_barrier + explicit
//     s_waitcnt vmcnt(8) (never drain to 0 mid-loop). This removes the
//     __syncthreads vmcnt(0) drain that exposed L2 latency twice per K-tile.
// ---------------------------------------------------------------------------

#define D_MODEL 1024
#define D_FF    4096
#define M_ROWS  16384
#define MC      4096

typedef _Float16 half8 __attribute__((ext_vector_type(8)));
typedef _Float16 half4 __attribute__((ext_vector_type(4)));
typedef float    floatx4 __attribute__((ext_vector_type(4)));

// s_waitcnt simm16 (gfx9): [3:0] vmcnt lo, [6:4] expcnt, [11:8] lgkmcnt
#define WAIT_VM8 0x0F78  // vmcnt<=8, expcnt/lgkmcnt no-wait
#define WAIT_VM0 0x0F70  // vmcnt<=0

// async global->LDS, 16B/lane; LDS dst = wave-uniform base + lane*16 (m97)
__device__ __forceinline__ void gld_lds16(const void* g, void* l) {
  __builtin_amdgcn_global_load_lds(
      (const __attribute__((address_space(1))) void*)g,
      (__attribute__((address_space(3))) void*)l, 16, 0, 0);
}

// ---------------------------------------------------------------------------
// rmsnorm (fp32 in) + hi/lo fp16 split. One wave per row of 1024.
// ---------------------------------------------------------------------------
#define MB_X (M_ROWS / 4)
#define MB_W (D_FF / 4)
__global__ __launch_bounds__(256) void rmsnorm_split_kernel(
    const float* __restrict__ X, _Float16* __restrict__ XH,
    _Float16* __restrict__ XL, const float* __restrict__ W,
    _Float16* __restrict__ WH, _Float16* __restrict__ WL) {
  const int lane = threadIdx.x & 63;
  const bool isW = blockIdx.x >= MB_X;
  const long row = (long)(isW ? blockIdx.x - MB_X : blockIdx.x) * 4 +
                   (threadIdx.x >> 6);
  const float* x = (isW ? W : X) + row * D_MODEL;
  _Float16* YH = (isW ? WH : XH) + row * D_MODEL;
  _Float16* YL = (isW ? WL : XL) + row * D_MODEL;

  float v[16];
  float ss = 0.f;
#pragma unroll
  for (int s = 0; s < 4; s++) {
    const float4 f = *(const float4*)(x + s * 256 + lane * 4);
    v[s * 4 + 0] = f.x; v[s * 4 + 1] = f.y;
    v[s * 4 + 2] = f.z; v[s * 4 + 3] = f.w;
    ss += f.x * f.x + f.y * f.y + f.z * f.z + f.w * f.w;
  }
#pragma unroll
  for (int off = 32; off >= 1; off >>= 1) ss += __shfl_xor(ss, off);
  const float inv = rsqrtf(ss * (1.0f / D_MODEL) + 1e-6f);
#pragma unroll
  for (int s = 0; s < 4; s++) {
    half4 h, l;
#pragma unroll
    for (int j = 0; j < 4; j++) {
      const float t = v[s * 4 + j] * inv;
      const _Float16 hi = (_Float16)t;
      h[j] = hi;
      l[j] = (_Float16)(t - (float)hi);
    }
    *(half4*)(YH + s * 256 + lane * 4) = h;
    *(half4*)(YL + s * 256 + lane * 4) = l;
  }
}

// ---------------------------------------------------------------------------
// transpose w [4096,1024] fp32 -> wT [1024,4096] fp16 (unnormalized, GEMM2 B)
// ---------------------------------------------------------------------------
__global__ __launch_bounds__(256) void transpose_kernel(
    const float* __restrict__ W, _Float16* __restrict__ WT) {
  __shared__ _Float16 tile[32][33];
  const int tx = threadIdx.x & 31;
  const int ty = threadIdx.x >> 5;  // 0..7
  const int d0 = blockIdx.x * 32;
  const int c0 = blockIdx.y * 32;
#pragma unroll
  for (int i = 0; i < 32; i += 8)
    tile[ty + i][tx] = (_Float16)W[(long)(c0 + ty + i) * D_MODEL + d0 + tx];
  __syncthreads();
#pragma unroll
  for (int i = 0; i < 32; i += 8)
    WT[(long)(d0 + ty + i) * D_FF + c0 + tx] = tile[tx][ty + i];
}

// ---------------------------------------------------------------------------
// GEMM K-loop: m97 tile shape + R2 XOR swizzle + R4 LDS double-buffer.
// LDS slot (row, k8s) holds global data (row, k8s ^ (row&7)); swizzle applied
// by permuting the *global source* lane address (scol). Fragment reads XOR
// the k-offset with m16&7 -> conflict-free ds_read_b128.
// ---------------------------------------------------------------------------

// GEMM1 (compensated): S[4096,4096] fp32, 3 segments of K=1024, T=48 tiles.
__global__ __launch_bounds__(256, 2) void gemm1_kernel(
    const _Float16* __restrict__ XH, const _Float16* __restrict__ XL,
    const _Float16* __restrict__ WH, const _Float16* __restrict__ WL,
    float* __restrict__ S) {
  constexpr int BK = 64, T = 48;
  __shared__ _Float16 As[2][128 * BK];
  __shared__ _Float16 Bs[2][128 * BK];
  const int tid = threadIdx.x;
  const int wave = tid >> 6, lane = tid & 63;
  const long rowBase = (long)blockIdx.y * 128;
  const long colBase = (long)blockIdx.x * 128;
  const int srow = lane >> 3;
  const int scol = ((lane & 7) ^ (lane >> 3)) * 8;  // XOR-swizzled source col
  const long aoff = (rowBase + wave * 32 + srow) * (long)D_MODEL + scol;
  const long boff = (colBase + wave * 32 + srow) * (long)D_MODEL + scol;
  const int ldsOff = wave * 2048 + lane * 8;
  const int wr = wave >> 1, wc = wave & 1;
  const int m16 = lane & 15, q = lane >> 4;
  const int mx7 = m16 & 7;

  const _Float16* Asegs[3] = {XH + aoff, XL + aoff, XH + aoff};
  const _Float16* Bsegs[3] = {WH + boff, WH + boff, WL + boff};

  floatx4 acc[4][4] = {};

  // issue staging loads for flat tile t into buffer p
  auto issue = [&](int t, int p) {
    const _Float16* Ag = Asegs[t >> 4] + (t & 15) * BK;
    const _Float16* Bg = Bsegs[t >> 4] + (t & 15) * BK;
    _Float16* Ad = &As[p][ldsOff];
    _Float16* Bd = &Bs[p][ldsOff];
#pragma unroll
    for (int i = 0; i < 4; i++) {
      gld_lds16(Ag + i * 8 * D_MODEL, Ad + i * 512);
      gld_lds16(Bg + i * 8 * D_MODEL, Bd + i * 512);
    }
  };

  issue(0, 0);
  for (int t = 0; t < T; t++) {
    const int p = t & 1;
    if (t < T - 1) {
      issue(t + 1, 1 - p);
      __builtin_amdgcn_s_waitcnt(WAIT_VM8);  // tile t's 8 loads done
    } else {
      __builtin_amdgcn_s_waitcnt(WAIT_VM0);
    }
    __builtin_amdgcn_s_barrier();  // all waves' tile-t slices visible
#pragma unroll
    for (int ks = 0; ks < 2; ks++) {
      const int kx = ((ks * 4 + q) ^ mx7) * 8;
      half8 a[4], b[4];
#pragma unroll
      for (int mi = 0; mi < 4; mi++)
        a[mi] = *(const half8*)(&As[p][(wr * 64 + mi * 16 + m16) * BK + kx]);
#pragma unroll
      for (int ni = 0; ni < 4; ni++)
        b[ni] = *(const half8*)(&Bs[p][(wc * 64 + ni * 16 + m16) * BK + kx]);
#pragma unroll
      for (int mi = 0; mi < 4; mi++)
#pragma unroll
        for (int ni = 0; ni < 4; ni++)
          acc[mi][ni] = __builtin_amdgcn_mfma_f32_16x16x32_f16(
              a[mi], b[ni], acc[mi][ni], 0, 0, 0);
    }
    if (t < T - 1) __builtin_amdgcn_s_barrier();  // done reading buf p
  }

  // C/D frag: col = lane&15, row = quad*4 + reg  [m89/m91 verified]
#pragma unroll
  for (int mi = 0; mi < 4; mi++)
#pragma unroll
    for (int r = 0; r < 4; r++) {
      const long rr = rowBase + wr * 64 + mi * 16 + q * 4 + r;
#pragma unroll
      for (int ni = 0; ni < 4; ni++)
        S[rr * D_FF + colBase + wc * 64 + ni * 16 + m16] = acc[mi][ni][r];
    }
}

// GEMM2: O[4096,1024] fp32 += P[4096, lda 8192] @ WT[1024,4096]^T
// split-K=2 (blockIdx.z), HW f32 atomics into pre-zeroed O. T=32 tiles.
__global__ __launch_bounds__(256, 2) void gemm2_kernel(
    const _Float16* __restrict__ P, const _Float16* __restrict__ WT,
    float* __restrict__ O) {
  constexpr int BK = 64, K = D_FF, LDA = 2 * D_FF, T = 32;
  __shared__ _Float16 As[2][128 * BK];
  __shared__ _Float16 Bs[2][128 * BK];
  const int tid = threadIdx.x;
  const int wave = tid >> 6, lane = tid & 63;
  const long rowBase = (long)blockIdx.y * 128;
  const long colBase = (long)blockIdx.x * 128;
  const int k0 = blockIdx.z * (T * BK);
  const int srow = lane >> 3;
  const int scol = ((lane & 7) ^ (lane >> 3)) * 8;
  const _Float16* Ag0 = P + (rowBase + wave * 32 + srow) * (long)LDA + scol + k0;
  const _Float16* Bg0 = WT + (colBase + wave * 32 + srow) * (long)K + scol + k0;
  const int ldsOff = wave * 2048 + lane * 8;
  const int wr = wave >> 1, wc = wave & 1;
  const int m16 = lane & 15, q = lane >> 4;
  const int mx7 = m16 & 7;

  floatx4 acc[4][4] = {};

  auto issue = [&](int t, int p) {
    const _Float16* Ag = Ag0 + t * BK;
    const _Float16* Bg = Bg0 + t * BK;
    _Float16* Ad = &As[p][ldsOff];
    _Float16* Bd = &Bs[p][ldsOff];
#pragma unroll
    for (int i = 0; i < 4; i++) {
      gld_lds16(Ag + (long)i * 8 * LDA, Ad + i * 512);
      gld_lds16(Bg + (long)i * 8 * K, Bd + i * 512);
    }
  };

  issue(0, 0);
  for (int t = 0; t < T; t++) {
    const int p = t & 1;
    if (t < T - 1) {
      issue(t + 1, 1 - p);
      __builtin_amdgcn_s_waitcnt(WAIT_VM8);
    } else {
      __builtin_amdgcn_s_waitcnt(WAIT_VM0);
    }
    __builtin_amdgcn_s_barrier();
#pragma unroll
    for (int ks = 0; ks < 2; ks++) {
      const int kx = ((ks * 4 + q) ^ mx7) * 8;
      half8 a[4], b[4];
#pragma unroll
      for (int mi = 0; mi < 4; mi++)
        a[mi] = *(const half8*)(&As[p][(wr * 64 + mi * 16 + m16) * BK + kx]);
#pragma unroll
      for (int ni = 0; ni < 4; ni++)
        b[ni] = *(const half8*)(&Bs[p][(wc * 64 + ni * 16 + m16) * BK + kx]);
#pragma unroll
      for (int mi = 0; mi < 4; mi++)
#pragma unroll
        for (int ni = 0; ni < 4; ni++)
          acc[mi][ni] = __builtin_amdgcn_mfma_f32_16x16x32_f16(
              a[mi], b[ni], acc[mi][ni], 0, 0, 0);
    }
    if (t < T - 1) __builtin_amdgcn_s_barrier();
  }

#pragma unroll
  for (int mi = 0; mi < 4; mi++)
#pragma unroll
    for (int r = 0; r < 4; r++) {
      const long rr = rowBase + wr * 64 + mi * 16 + q * 4 + r;
#pragma unroll
      for (int ni = 0; ni < 4; ni++)
        unsafeAtomicAdd(&O[rr * D_MODEL + colBase + wc * 64 + ni * 16 + m16],
                        acc[mi][ni][r]);
    }
}

// ---------------------------------------------------------------------------
// softmax over rows of 4096: fp32 S in, fp16 P out in-place at row start.
// ---------------------------------------------------------------------------
__global__ __launch_bounds__(256) void softmax_kernel(float* __restrict__ S) {
  float* s = S + (long)blockIdx.x * D_FF;
  const int t = threadIdx.x;
  const int lane = t & 63, wave = t >> 6;
  __shared__ float redm[4], redl[4];

  float v[16];
  float mx = -3.4e38f;
#pragma unroll
  for (int seg = 0; seg < 4; seg++) {
    const float4 f = *(const float4*)(s + seg * 1024 + t * 4);
    v[seg * 4 + 0] = f.x; v[seg * 4 + 1] = f.y;
    v[seg * 4 + 2] = f.z; v[seg * 4 + 3] = f.w;
  }
#pragma unroll
  for (int j = 0; j < 16; j++) mx = fmaxf(mx, v[j]);
#pragma unroll
  for (int off = 32; off >= 1; off >>= 1) mx = fmaxf(mx, __shfl_xor(mx, off));
  if (lane == 0) redm[wave] = mx;
  __syncthreads();
  const float m = fmaxf(fmaxf(redm[0], redm[1]), fmaxf(redm[2], redm[3]));

  float sum = 0.f;
#pragma unroll
  for (int j = 0; j < 16; j++) {
    v[j] = __expf(v[j] - m);
    sum += v[j];
  }
#pragma unroll
  for (int off = 32; off >= 1; off >>= 1) sum += __shfl_xor(sum, off);
  if (lane == 0) redl[wave] = sum;
  __syncthreads();
  const float inv = 1.f / (redl[0] + redl[1] + redl[2] + redl[3]);

  _Float16* p = (_Float16*)s;  // all reads of this row completed above
#pragma unroll
  for (int seg = 0; seg < 4; seg++) {
    half4 h;
#pragma unroll
    for (int j = 0; j < 4; j++) h[j] = (_Float16)(v[seg * 4 + j] * inv);
    *(half4*)(p + seg * 1024 + t * 4) = h;
  }
}

// ---------------------------------------------------------------------------
extern "C" void kernel_launch(void* const* d_in, const int* in_sizes, int n_in,
                              void* d_out, int out_size, void* d_ws, size_t ws_size,
                              hipStream_t stream) {
  const float* x = (const float*)d_in[0];  // [16384,1024] fp32
  const float* w = (const float*)d_in[1];  // [4096,1024] fp32
  float* out = (float*)d_out;              // [16384,1024] fp32

  // ws layout: xh 32Mi | xl 32Mi | wh 8Mi | wl 8Mi | wT 8Mi | S 64Mi = 152Mi
  const size_t NEED = 152ull << 20;
  if (ws_size < NEED) return;

  char* ws = (char*)d_ws;
  _Float16* xh = (_Float16*)(ws);
  _Float16* xl = (_Float16*)(ws + (32ull << 20));
  _Float16* wh = (_Float16*)(ws + (64ull << 20));
  _Float16* wl = (_Float16*)(ws + (72ull << 20));
  _Float16* wT = (_Float16*)(ws + (80ull << 20));
  float*    S  = (float*)   (ws + (88ull << 20));

  // gemm2 accumulates via atomics -> zero d_out first (graph-capture safe)
  hipMemsetAsync(d_out, 0, (size_t)M_ROWS * D_MODEL * sizeof(float), stream);

  hipLaunchKernelGGL(rmsnorm_split_kernel, dim3(MB_X + MB_W), dim3(256), 0,
                     stream, x, xh, xl, w, wh, wl);
  hipLaunchKernelGGL(transpose_kernel, dim3(D_MODEL / 32, D_FF / 32), dim3(256),
                     0, stream, w, wT);

  for (int c = 0; c < M_ROWS / MC; c++) {
    const long ro = (long)c * MC;
    hipLaunchKernelGGL(gemm1_kernel, dim3(D_FF / 128, MC / 128), dim3(256), 0,
                       stream, xh + ro * D_MODEL, xl + ro * D_MODEL, wh, wl, S);
    hipLaunchKernelGGL(softmax_kernel, dim3(MC), dim3(256), 0, stream, S);
    hipLaunchKernelGGL(gemm2_kernel, dim3(D_MODEL / 128, MC / 128, 2),
                       dim3(256), 0, stream, (const _Float16*)S, wT,
                       out + ro * D_MODEL);
  }
}

// Round 6
// 712.820 us; speedup vs baseline: 1.2277x; 1.2277x over previous
//
#include <hip/hip_runtime.h>
#include <hip/hip_fp16.h>

// ---------------------------------------------------------------------------
// VQFFN1: out = softmax(rmsnorm(x) @ rmsnorm(w)^T) @ w
//   x: [16384,1024] fp32   w: [4096,1024] fp32   out: [16384,1024] fp32
// fp32 scores; GEMM2 plain fp16 + split-K=2 + f32 HW atomics.
// R2: XOR-swizzled LDS (bank conflicts 3.8e7 -> 0).
// R4 (reverted in R5): explicit LDS dbuf cut co-resident blocks 2.6->1.7 and
//     regressed 103->119 us; implicit inter-block overlap (m114) wins.
// R5: GEMM1 = xn*wh with x fully compensated: S = xh*wh + xl*wh (the xh*wl
//     term dropped; residual = w's fp16 rounding, sigma~9e-3/score, 6.7-sigma
//     safe). Both passes share one staged WH tile and one b-frag LDS read ->
//     FLOPs x2/3, LDS read traffic /2.7, B fetch /2.
// ---------------------------------------------------------------------------

#define D_MODEL 1024
#define D_FF    4096
#define M_ROWS  16384
#define MC      4096

typedef _Float16 half8 __attribute__((ext_vector_type(8)));
typedef _Float16 half4 __attribute__((ext_vector_type(4)));
typedef float    floatx4 __attribute__((ext_vector_type(4)));

// async global->LDS, 16B/lane; LDS dst = wave-uniform base + lane*16 (m97)
__device__ __forceinline__ void gld_lds16(const void* g, void* l) {
  __builtin_amdgcn_global_load_lds(
      (const __attribute__((address_space(1))) void*)g,
      (__attribute__((address_space(3))) void*)l, 16, 0, 0);
}

// ---------------------------------------------------------------------------
// rmsnorm (fp32 in) + hi/lo fp16 split. One wave per row of 1024.
// ---------------------------------------------------------------------------
#define MB_X (M_ROWS / 4)
#define MB_W (D_FF / 4)
__global__ __launch_bounds__(256) void rmsnorm_split_kernel(
    const float* __restrict__ X, _Float16* __restrict__ XH,
    _Float16* __restrict__ XL, const float* __restrict__ W,
    _Float16* __restrict__ WH, _Float16* __restrict__ WL) {
  const int lane = threadIdx.x & 63;
  const bool isW = blockIdx.x >= MB_X;
  const long row = (long)(isW ? blockIdx.x - MB_X : blockIdx.x) * 4 +
                   (threadIdx.x >> 6);
  const float* x = (isW ? W : X) + row * D_MODEL;
  _Float16* YH = (isW ? WH : XH) + row * D_MODEL;
  _Float16* YL = (isW ? WL : XL) + row * D_MODEL;

  float v[16];
  float ss = 0.f;
#pragma unroll
  for (int s = 0; s < 4; s++) {
    const float4 f = *(const float4*)(x + s * 256 + lane * 4);
    v[s * 4 + 0] = f.x; v[s * 4 + 1] = f.y;
    v[s * 4 + 2] = f.z; v[s * 4 + 3] = f.w;
    ss += f.x * f.x + f.y * f.y + f.z * f.z + f.w * f.w;
  }
#pragma unroll
  for (int off = 32; off >= 1; off >>= 1) ss += __shfl_xor(ss, off);
  const float inv = rsqrtf(ss * (1.0f / D_MODEL) + 1e-6f);
#pragma unroll
  for (int s = 0; s < 4; s++) {
    half4 h, l;
#pragma unroll
    for (int j = 0; j < 4; j++) {
      const float t = v[s * 4 + j] * inv;
      const _Float16 hi = (_Float16)t;
      h[j] = hi;
      l[j] = (_Float16)(t - (float)hi);
    }
    *(half4*)(YH + s * 256 + lane * 4) = h;
    *(half4*)(YL + s * 256 + lane * 4) = l;
  }
}

// ---------------------------------------------------------------------------
// transpose w [4096,1024] fp32 -> wT [1024,4096] fp16 (unnormalized, GEMM2 B)
// ---------------------------------------------------------------------------
__global__ __launch_bounds__(256) void transpose_kernel(
    const float* __restrict__ W, _Float16* __restrict__ WT) {
  __shared__ _Float16 tile[32][33];
  const int tx = threadIdx.x & 31;
  const int ty = threadIdx.x >> 5;  // 0..7
  const int d0 = blockIdx.x * 32;
  const int c0 = blockIdx.y * 32;
#pragma unroll
  for (int i = 0; i < 32; i += 8)
    tile[ty + i][tx] = (_Float16)W[(long)(c0 + ty + i) * D_MODEL + d0 + tx];
  __syncthreads();
#pragma unroll
  for (int i = 0; i < 32; i += 8)
    WT[(long)(d0 + ty + i) * D_FF + c0 + tx] = tile[tx][ty + i];
}

// ---------------------------------------------------------------------------
// GEMM K-loop: m97 structure + R2 XOR swizzle (single LDS buffer).
// LDS slot (row, k8s) holds global data (row, k8s ^ (row&7)); swizzle applied
// by permuting the *global source* lane address (scol). Fragment reads XOR
// the k-offset with m16&7 -> conflict-free ds_read_b128.
// ---------------------------------------------------------------------------

// GEMM1: S[4096,4096] fp32 = (xh + xl) @ wh^T over K=1024; per K-tile the
// staged WH tile and its b-frags serve both the xh and xl MFMA passes.
__global__ __launch_bounds__(256, 2) void gemm1_kernel(
    const _Float16* __restrict__ XH, const _Float16* __restrict__ XL,
    const _Float16* __restrict__ WH, float* __restrict__ S) {
  constexpr int BK = 64;
  __shared__ _Float16 Ah[128 * BK];  // xh tile
  __shared__ _Float16 Al[128 * BK];  // xl tile
  __shared__ _Float16 Bs[128 * BK];  // wh tile
  const int tid = threadIdx.x;
  const int wave = tid >> 6, lane = tid & 63;
  const long rowBase = (long)blockIdx.y * 128;
  const long colBase = (long)blockIdx.x * 128;
  const int srow = lane >> 3;
  const int scol = ((lane & 7) ^ (lane >> 3)) * 8;  // XOR-swizzled source col
  const _Float16* AgH = XH + (rowBase + wave * 32 + srow) * (long)D_MODEL + scol;
  const _Float16* AgL = XL + (rowBase + wave * 32 + srow) * (long)D_MODEL + scol;
  const _Float16* Bg  = WH + (colBase + wave * 32 + srow) * (long)D_MODEL + scol;
  const int ldsOff = wave * 2048 + lane * 8;
  const int wr = wave >> 1, wc = wave & 1;
  const int m16 = lane & 15, q = lane >> 4;
  const int mx7 = m16 & 7;

  floatx4 acc[4][4] = {};

  for (int kt = 0; kt < D_MODEL; kt += BK) {
#pragma unroll
    for (int i = 0; i < 4; i++) {
      gld_lds16(AgH + i * 8 * D_MODEL + kt, Ah + ldsOff + i * 512);
      gld_lds16(AgL + i * 8 * D_MODEL + kt, Al + ldsOff + i * 512);
      gld_lds16(Bg  + i * 8 * D_MODEL + kt, Bs + ldsOff + i * 512);
    }
    __syncthreads();
#pragma unroll
    for (int ks = 0; ks < 2; ks++) {
      const int kx = ((ks * 4 + q) ^ mx7) * 8;
      half8 a[4], c[4], b[4];
#pragma unroll
      for (int ni = 0; ni < 4; ni++)
        b[ni] = *(const half8*)(&Bs[(wc * 64 + ni * 16 + m16) * BK + kx]);
#pragma unroll
      for (int mi = 0; mi < 4; mi++)
        a[mi] = *(const half8*)(&Ah[(wr * 64 + mi * 16 + m16) * BK + kx]);
#pragma unroll
      for (int mi = 0; mi < 4; mi++)
#pragma unroll
        for (int ni = 0; ni < 4; ni++)
          acc[mi][ni] = __builtin_amdgcn_mfma_f32_16x16x32_f16(
              a[mi], b[ni], acc[mi][ni], 0, 0, 0);
#pragma unroll
      for (int mi = 0; mi < 4; mi++)
        c[mi] = *(const half8*)(&Al[(wr * 64 + mi * 16 + m16) * BK + kx]);
#pragma unroll
      for (int mi = 0; mi < 4; mi++)
#pragma unroll
        for (int ni = 0; ni < 4; ni++)
          acc[mi][ni] = __builtin_amdgcn_mfma_f32_16x16x32_f16(
              c[mi], b[ni], acc[mi][ni], 0, 0, 0);
    }
    __syncthreads();
  }

  // C/D frag: col = lane&15, row = quad*4 + reg  [m89/m91 verified]
#pragma unroll
  for (int mi = 0; mi < 4; mi++)
#pragma unroll
    for (int r = 0; r < 4; r++) {
      const long rr = rowBase + wr * 64 + mi * 16 + q * 4 + r;
#pragma unroll
      for (int ni = 0; ni < 4; ni++)
        S[rr * D_FF + colBase + wc * 64 + ni * 16 + m16] = acc[mi][ni][r];
    }
}

// GEMM2: O[4096,1024] fp32 += P[4096, lda 8192] @ WT[1024,4096]^T
// split-K=2 (blockIdx.z), HW f32 atomics into pre-zeroed O. (R3 form.)
__global__ __launch_bounds__(256, 2) void gemm2_kernel(
    const _Float16* __restrict__ P, const _Float16* __restrict__ WT,
    float* __restrict__ O) {
  constexpr int BK = 64, K = D_FF, LDA = 2 * D_FF, KSPLIT = 2048;
  __shared__ _Float16 As[128 * BK];
  __shared__ _Float16 Bs[128 * BK];
  const int tid = threadIdx.x;
  const int wave = tid >> 6, lane = tid & 63;
  const long rowBase = (long)blockIdx.y * 128;
  const long colBase = (long)blockIdx.x * 128;
  const int k0 = blockIdx.z * KSPLIT;
  const int srow = lane >> 3;
  const int scol = ((lane & 7) ^ (lane >> 3)) * 8;
  const _Float16* Ag = P + (rowBase + wave * 32 + srow) * (long)LDA + scol;
  const _Float16* Bg = WT + (colBase + wave * 32 + srow) * (long)K + scol;
  _Float16* AsW = As + wave * 2048 + lane * 8;
  _Float16* BsW = Bs + wave * 2048 + lane * 8;
  const int wr = wave >> 1, wc = wave & 1;
  const int m16 = lane & 15, q = lane >> 4;
  const int mx7 = m16 & 7;

  floatx4 acc[4][4] = {};

  for (int kt = k0; kt < k0 + KSPLIT; kt += BK) {
#pragma unroll
    for (int i = 0; i < 4; i++) {
      gld_lds16(Ag + (long)i * 8 * LDA + kt, AsW + i * 512);
      gld_lds16(Bg + (long)i * 8 * K + kt, BsW + i * 512);
    }
    __syncthreads();
#pragma unroll
    for (int ks = 0; ks < 2; ks++) {
      const int kx = ((ks * 4 + q) ^ mx7) * 8;
      half8 a[4], b[4];
#pragma unroll
      for (int mi = 0; mi < 4; mi++)
        a[mi] = *(const half8*)(&As[(wr * 64 + mi * 16 + m16) * BK + kx]);
#pragma unroll
      for (int ni = 0; ni < 4; ni++)
        b[ni] = *(const half8*)(&Bs[(wc * 64 + ni * 16 + m16) * BK + kx]);
#pragma unroll
      for (int mi = 0; mi < 4; mi++)
#pragma unroll
        for (int ni = 0; ni < 4; ni++)
          acc[mi][ni] = __builtin_amdgcn_mfma_f32_16x16x32_f16(
              a[mi], b[ni], acc[mi][ni], 0, 0, 0);
    }
    __syncthreads();
  }

#pragma unroll
  for (int mi = 0; mi < 4; mi++)
#pragma unroll
    for (int r = 0; r < 4; r++) {
      const long rr = rowBase + wr * 64 + mi * 16 + q * 4 + r;
#pragma unroll
      for (int ni = 0; ni < 4; ni++)
        unsafeAtomicAdd(&O[rr * D_MODEL + colBase + wc * 64 + ni * 16 + m16],
                        acc[mi][ni][r]);
    }
}

// ---------------------------------------------------------------------------
// softmax over rows of 4096: fp32 S in, fp16 P out in-place at row start.
// ---------------------------------------------------------------------------
__global__ __launch_bounds__(256) void softmax_kernel(float* __restrict__ S) {
  float* s = S + (long)blockIdx.x * D_FF;
  const int t = threadIdx.x;
  const int lane = t & 63, wave = t >> 6;
  __shared__ float redm[4], redl[4];

  float v[16];
  float mx = -3.4e38f;
#pragma unroll
  for (int seg = 0; seg < 4; seg++) {
    const float4 f = *(const float4*)(s + seg * 1024 + t * 4);
    v[seg * 4 + 0] = f.x; v[seg * 4 + 1] = f.y;
    v[seg * 4 + 2] = f.z; v[seg * 4 + 3] = f.w;
  }
#pragma unroll
  for (int j = 0; j < 16; j++) mx = fmaxf(mx, v[j]);
#pragma unroll
  for (int off = 32; off >= 1; off >>= 1) mx = fmaxf(mx, __shfl_xor(mx, off));
  if (lane == 0) redm[wave] = mx;
  __syncthreads();
  const float m = fmaxf(fmaxf(redm[0], redm[1]), fmaxf(redm[2], redm[3]));

  float sum = 0.f;
#pragma unroll
  for (int j = 0; j < 16; j++) {
    v[j] = __expf(v[j] - m);
    sum += v[j];
  }
#pragma unroll
  for (int off = 32; off >= 1; off >>= 1) sum += __shfl_xor(sum, off);
  if (lane == 0) redl[wave] = sum;
  __syncthreads();
  const float inv = 1.f / (redl[0] + redl[1] + redl[2] + redl[3]);

  _Float16* p = (_Float16*)s;  // all reads of this row completed above
#pragma unroll
  for (int seg = 0; seg < 4; seg++) {
    half4 h;
#pragma unroll
    for (int j = 0; j < 4; j++) h[j] = (_Float16)(v[seg * 4 + j] * inv);
    *(half4*)(p + seg * 1024 + t * 4) = h;
  }
}

// ---------------------------------------------------------------------------
extern "C" void kernel_launch(void* const* d_in, const int* in_sizes, int n_in,
                              void* d_out, int out_size, void* d_ws, size_t ws_size,
                              hipStream_t stream) {
  const float* x = (const float*)d_in[0];  // [16384,1024] fp32
  const float* w = (const float*)d_in[1];  // [4096,1024] fp32
  float* out = (float*)d_out;              // [16384,1024] fp32

  // ws layout: xh 32Mi | xl 32Mi | wh 8Mi | wl 8Mi | wT 8Mi | S 64Mi = 152Mi
  const size_t NEED = 152ull << 20;
  if (ws_size < NEED) return;

  char* ws = (char*)d_ws;
  _Float16* xh = (_Float16*)(ws);
  _Float16* xl = (_Float16*)(ws + (32ull << 20));
  _Float16* wh = (_Float16*)(ws + (64ull << 20));
  _Float16* wl = (_Float16*)(ws + (72ull << 20));  // written, unused (R5)
  _Float16* wT = (_Float16*)(ws + (80ull << 20));
  float*    S  = (float*)   (ws + (88ull << 20));

  // gemm2 accumulates via atomics -> zero d_out first (graph-capture safe)
  hipMemsetAsync(d_out, 0, (size_t)M_ROWS * D_MODEL * sizeof(float), stream);

  hipLaunchKernelGGL(rmsnorm_split_kernel, dim3(MB_X + MB_W), dim3(256), 0,
                     stream, x, xh, xl, w, wh, wl);
  hipLaunchKernelGGL(transpose_kernel, dim3(D_MODEL / 32, D_FF / 32), dim3(256),
                     0, stream, w, wT);

  for (int c = 0; c < M_ROWS / MC; c++) {
    const long ro = (long)c * MC;
    hipLaunchKernelGGL(gemm1_kernel, dim3(D_FF / 128, MC / 128), dim3(256), 0,
                       stream, xh + ro * D_MODEL, xl + ro * D_MODEL, wh, S);
    hipLaunchKernelGGL(softmax_kernel, dim3(MC), dim3(256), 0, stream, S);
    hipLaunchKernelGGL(gemm2_kernel, dim3(D_MODEL / 128, MC / 128, 2),
                       dim3(256), 0, stream, (const _Float16*)S, wT,
                       out + ro * D_MODEL);
  }
}

// Round 7
// 703.202 us; speedup vs baseline: 1.2445x; 1.0137x over previous
//
#include <hip/hip_runtime.h>
#include <hip/hip_fp16.h>

// ---------------------------------------------------------------------------
// VQFFN1: out = softmax(rmsnorm(x) @ rmsnorm(w)^T) @ w
//   x: [16384,1024] fp32   w: [4096,1024] fp32   out: [16384,1024] fp32
// fp32 scores; GEMM2 plain fp16 + split-K=2 + f32 HW atomics.
// R2: XOR-swizzled LDS (bank conflicts 3.8e7 -> 0).
// R4 (reverted): explicit LDS dbuf cut occupancy, 103->119 us.
// R5: S = (xh + xl) @ wh^T (xh*wl dropped; residual = w fp16 rounding,
//     ~9e-3/score, safe); shared WH tile + b-frags across both passes.
// R6: gemm1 128x256 block tile (wave 64x128, acc[4][8]): per ks 16 LDS reads
//     feed 64 MFMA (4096 FLOP/B vs 2731) -- MFMA & LDS-read were co-critical
//     at 128x128. LDS 64 KB, still 2 blocks/CU; grid (16,32)=512 = 2/CU.
// ---------------------------------------------------------------------------

#define D_MODEL 1024
#define D_FF    4096
#define M_ROWS  16384
#define MC      4096

typedef _Float16 half8 __attribute__((ext_vector_type(8)));
typedef _Float16 half4 __attribute__((ext_vector_type(4)));
typedef float    floatx4 __attribute__((ext_vector_type(4)));

// async global->LDS, 16B/lane; LDS dst = wave-uniform base + lane*16 (m97)
__device__ __forceinline__ void gld_lds16(const void* g, void* l) {
  __builtin_amdgcn_global_load_lds(
      (const __attribute__((address_space(1))) void*)g,
      (__attribute__((address_space(3))) void*)l, 16, 0, 0);
}

// ---------------------------------------------------------------------------
// rmsnorm (fp32 in) + hi/lo fp16 split. One wave per row of 1024.
// ---------------------------------------------------------------------------
#define MB_X (M_ROWS / 4)
#define MB_W (D_FF / 4)
__global__ __launch_bounds__(256) void rmsnorm_split_kernel(
    const float* __restrict__ X, _Float16* __restrict__ XH,
    _Float16* __restrict__ XL, const float* __restrict__ W,
    _Float16* __restrict__ WH, _Float16* __restrict__ WL) {
  const int lane = threadIdx.x & 63;
  const bool isW = blockIdx.x >= MB_X;
  const long row = (long)(isW ? blockIdx.x - MB_X : blockIdx.x) * 4 +
                   (threadIdx.x >> 6);
  const float* x = (isW ? W : X) + row * D_MODEL;
  _Float16* YH = (isW ? WH : XH) + row * D_MODEL;
  _Float16* YL = (isW ? WL : XL) + row * D_MODEL;

  float v[16];
  float ss = 0.f;
#pragma unroll
  for (int s = 0; s < 4; s++) {
    const float4 f = *(const float4*)(x + s * 256 + lane * 4);
    v[s * 4 + 0] = f.x; v[s * 4 + 1] = f.y;
    v[s * 4 + 2] = f.z; v[s * 4 + 3] = f.w;
    ss += f.x * f.x + f.y * f.y + f.z * f.z + f.w * f.w;
  }
#pragma unroll
  for (int off = 32; off >= 1; off >>= 1) ss += __shfl_xor(ss, off);
  const float inv = rsqrtf(ss * (1.0f / D_MODEL) + 1e-6f);
#pragma unroll
  for (int s = 0; s < 4; s++) {
    half4 h, l;
#pragma unroll
    for (int j = 0; j < 4; j++) {
      const float t = v[s * 4 + j] * inv;
      const _Float16 hi = (_Float16)t;
      h[j] = hi;
      l[j] = (_Float16)(t - (float)hi);
    }
    *(half4*)(YH + s * 256 + lane * 4) = h;
    *(half4*)(YL + s * 256 + lane * 4) = l;
  }
}

// ---------------------------------------------------------------------------
// transpose w [4096,1024] fp32 -> wT [1024,4096] fp16 (unnormalized, GEMM2 B)
// ---------------------------------------------------------------------------
__global__ __launch_bounds__(256) void transpose_kernel(
    const float* __restrict__ W, _Float16* __restrict__ WT) {
  __shared__ _Float16 tile[32][33];
  const int tx = threadIdx.x & 31;
  const int ty = threadIdx.x >> 5;  // 0..7
  const int d0 = blockIdx.x * 32;
  const int c0 = blockIdx.y * 32;
#pragma unroll
  for (int i = 0; i < 32; i += 8)
    tile[ty + i][tx] = (_Float16)W[(long)(c0 + ty + i) * D_MODEL + d0 + tx];
  __syncthreads();
#pragma unroll
  for (int i = 0; i < 32; i += 8)
    WT[(long)(d0 + ty + i) * D_FF + c0 + tx] = tile[tx][ty + i];
}

// ---------------------------------------------------------------------------
// GEMM K-loops: m97 structure + R2 XOR swizzle (single LDS buffer).
// LDS slot (row, k8s) holds global data (row, k8s ^ (row&7)); swizzle applied
// by permuting the *global source* lane address (scol). Fragment reads XOR
// the k-offset with m16&7 -> conflict-free ds_read_b128.
// ---------------------------------------------------------------------------

// GEMM1: S[4096,4096] fp32 = (xh + xl) @ wh^T over K=1024.
// 128x256 block tile; per K-tile the staged WH tile + b-frags serve both the
// xh and xl MFMA passes; wave-tile 64x128 (acc[4][8]).
__global__ __launch_bounds__(256, 2) void gemm1_kernel(
    const _Float16* __restrict__ XH, const _Float16* __restrict__ XL,
    const _Float16* __restrict__ WH, float* __restrict__ S) {
  constexpr int BK = 64;
  __shared__ _Float16 Ah[128 * BK];  // xh tile (16 KB)
  __shared__ _Float16 Al[128 * BK];  // xl tile (16 KB)
  __shared__ _Float16 Bs[256 * BK];  // wh tile (32 KB)
  const int tid = threadIdx.x;
  const int wave = tid >> 6, lane = tid & 63;
  const long rowBase = (long)blockIdx.y * 128;
  const long colBase = (long)blockIdx.x * 256;
  const int srow = lane >> 3;
  const int scol = ((lane & 7) ^ (lane >> 3)) * 8;  // XOR-swizzled source col
  const _Float16* AgH = XH + (rowBase + wave * 32 + srow) * (long)D_MODEL + scol;
  const _Float16* AgL = XL + (rowBase + wave * 32 + srow) * (long)D_MODEL + scol;
  const _Float16* Bg  = WH + (colBase + wave * 64 + srow) * (long)D_MODEL + scol;
  const int ldsOffA = wave * 2048 + lane * 8;  // 32 rows/wave
  const int ldsOffB = wave * 4096 + lane * 8;  // 64 rows/wave
  const int wr = wave >> 1, wc = wave & 1;
  const int m16 = lane & 15, q = lane >> 4;
  const int mx7 = m16 & 7;

  floatx4 acc[4][8] = {};

  for (int kt = 0; kt < D_MODEL; kt += BK) {
#pragma unroll
    for (int i = 0; i < 4; i++) {
      gld_lds16(AgH + i * 8 * D_MODEL + kt, Ah + ldsOffA + i * 512);
      gld_lds16(AgL + i * 8 * D_MODEL + kt, Al + ldsOffA + i * 512);
    }
#pragma unroll
    for (int i = 0; i < 8; i++)
      gld_lds16(Bg + i * 8 * D_MODEL + kt, Bs + ldsOffB + i * 512);
    __syncthreads();
#pragma unroll
    for (int ks = 0; ks < 2; ks++) {
      const int kx = ((ks * 4 + q) ^ mx7) * 8;
      half8 b[8], a[4];
#pragma unroll
      for (int ni = 0; ni < 8; ni++)
        b[ni] = *(const half8*)(&Bs[(wc * 128 + ni * 16 + m16) * BK + kx]);
#pragma unroll
      for (int mi = 0; mi < 4; mi++)
        a[mi] = *(const half8*)(&Ah[(wr * 64 + mi * 16 + m16) * BK + kx]);
#pragma unroll
      for (int mi = 0; mi < 4; mi++)
#pragma unroll
        for (int ni = 0; ni < 8; ni++)
          acc[mi][ni] = __builtin_amdgcn_mfma_f32_16x16x32_f16(
              a[mi], b[ni], acc[mi][ni], 0, 0, 0);
#pragma unroll
      for (int mi = 0; mi < 4; mi++)
        a[mi] = *(const half8*)(&Al[(wr * 64 + mi * 16 + m16) * BK + kx]);
#pragma unroll
      for (int mi = 0; mi < 4; mi++)
#pragma unroll
        for (int ni = 0; ni < 8; ni++)
          acc[mi][ni] = __builtin_amdgcn_mfma_f32_16x16x32_f16(
              a[mi], b[ni], acc[mi][ni], 0, 0, 0);
    }
    __syncthreads();
  }

  // C/D frag: col = lane&15, row = quad*4 + reg  [m89/m91 verified]
#pragma unroll
  for (int mi = 0; mi < 4; mi++)
#pragma unroll
    for (int r = 0; r < 4; r++) {
      const long rr = rowBase + wr * 64 + mi * 16 + q * 4 + r;
#pragma unroll
      for (int ni = 0; ni < 8; ni++)
        S[rr * D_FF + colBase + wc * 128 + ni * 16 + m16] = acc[mi][ni][r];
    }
}

// GEMM2: O[4096,1024] fp32 += P[4096, lda 8192] @ WT[1024,4096]^T
// 128x128, split-K=2 (blockIdx.z), HW f32 atomics into pre-zeroed O.
__global__ __launch_bounds__(256, 2) void gemm2_kernel(
    const _Float16* __restrict__ P, const _Float16* __restrict__ WT,
    float* __restrict__ O) {
  constexpr int BK = 64, K = D_FF, LDA = 2 * D_FF, KSPLIT = 2048;
  __shared__ _Float16 As[128 * BK];
  __shared__ _Float16 Bs[128 * BK];
  const int tid = threadIdx.x;
  const int wave = tid >> 6, lane = tid & 63;
  const long rowBase = (long)blockIdx.y * 128;
  const long colBase = (long)blockIdx.x * 128;
  const int k0 = blockIdx.z * KSPLIT;
  const int srow = lane >> 3;
  const int scol = ((lane & 7) ^ (lane >> 3)) * 8;
  const _Float16* Ag = P + (rowBase + wave * 32 + srow) * (long)LDA + scol;
  const _Float16* Bg = WT + (colBase + wave * 32 + srow) * (long)K + scol;
  _Float16* AsW = As + wave * 2048 + lane * 8;
  _Float16* BsW = Bs + wave * 2048 + lane * 8;
  const int wr = wave >> 1, wc = wave & 1;
  const int m16 = lane & 15, q = lane >> 4;
  const int mx7 = m16 & 7;

  floatx4 acc[4][4] = {};

  for (int kt = k0; kt < k0 + KSPLIT; kt += BK) {
#pragma unroll
    for (int i = 0; i < 4; i++) {
      gld_lds16(Ag + (long)i * 8 * LDA + kt, AsW + i * 512);
      gld_lds16(Bg + (long)i * 8 * K + kt, BsW + i * 512);
    }
    __syncthreads();
#pragma unroll
    for (int ks = 0; ks < 2; ks++) {
      const int kx = ((ks * 4 + q) ^ mx7) * 8;
      half8 a[4], b[4];
#pragma unroll
      for (int mi = 0; mi < 4; mi++)
        a[mi] = *(const half8*)(&As[(wr * 64 + mi * 16 + m16) * BK + kx]);
#pragma unroll
      for (int ni = 0; ni < 4; ni++)
        b[ni] = *(const half8*)(&Bs[(wc * 64 + ni * 16 + m16) * BK + kx]);
#pragma unroll
      for (int mi = 0; mi < 4; mi++)
#pragma unroll
        for (int ni = 0; ni < 4; ni++)
          acc[mi][ni] = __builtin_amdgcn_mfma_f32_16x16x32_f16(
              a[mi], b[ni], acc[mi][ni], 0, 0, 0);
    }
    __syncthreads();
  }

#pragma unroll
  for (int mi = 0; mi < 4; mi++)
#pragma unroll
    for (int r = 0; r < 4; r++) {
      const long rr = rowBase + wr * 64 + mi * 16 + q * 4 + r;
#pragma unroll
      for (int ni = 0; ni < 4; ni++)
        unsafeAtomicAdd(&O[rr * D_MODEL + colBase + wc * 64 + ni * 16 + m16],
                        acc[mi][ni][r]);
    }
}

// ---------------------------------------------------------------------------
// softmax over rows of 4096: fp32 S in, fp16 P out in-place at row start.
// ---------------------------------------------------------------------------
__global__ __launch_bounds__(256) void softmax_kernel(float* __restrict__ S) {
  float* s = S + (long)blockIdx.x * D_FF;
  const int t = threadIdx.x;
  const int lane = t & 63, wave = t >> 6;
  __shared__ float redm[4], redl[4];

  float v[16];
  float mx = -3.4e38f;
#pragma unroll
  for (int seg = 0; seg < 4; seg++) {
    const float4 f = *(const float4*)(s + seg * 1024 + t * 4);
    v[seg * 4 + 0] = f.x; v[seg * 4 + 1] = f.y;
    v[seg * 4 + 2] = f.z; v[seg * 4 + 3] = f.w;
  }
#pragma unroll
  for (int j = 0; j < 16; j++) mx = fmaxf(mx, v[j]);
#pragma unroll
  for (int off = 32; off >= 1; off >>= 1) mx = fmaxf(mx, __shfl_xor(mx, off));
  if (lane == 0) redm[wave] = mx;
  __syncthreads();
  const float m = fmaxf(fmaxf(redm[0], redm[1]), fmaxf(redm[2], redm[3]));

  float sum = 0.f;
#pragma unroll
  for (int j = 0; j < 16; j++) {
    v[j] = __expf(v[j] - m);
    sum += v[j];
  }
#pragma unroll
  for (int off = 32; off >= 1; off >>= 1) sum += __shfl_xor(sum, off);
  if (lane == 0) redl[wave] = sum;
  __syncthreads();
  const float inv = 1.f / (redl[0] + redl[1] + redl[2] + redl[3]);

  _Float16* p = (_Float16*)s;  // all reads of this row completed above
#pragma unroll
  for (int seg = 0; seg < 4; seg++) {
    half4 h;
#pragma unroll
    for (int j = 0; j < 4; j++) h[j] = (_Float16)(v[seg * 4 + j] * inv);
    *(half4*)(p + seg * 1024 + t * 4) = h;
  }
}

// ---------------------------------------------------------------------------
extern "C" void kernel_launch(void* const* d_in, const int* in_sizes, int n_in,
                              void* d_out, int out_size, void* d_ws, size_t ws_size,
                              hipStream_t stream) {
  const float* x = (const float*)d_in[0];  // [16384,1024] fp32
  const float* w = (const float*)d_in[1];  // [4096,1024] fp32
  float* out = (float*)d_out;              // [16384,1024] fp32

  // ws layout: xh 32Mi | xl 32Mi | wh 8Mi | wl 8Mi | wT 8Mi | S 64Mi = 152Mi
  const size_t NEED = 152ull << 20;
  if (ws_size < NEED) return;

  char* ws = (char*)d_ws;
  _Float16* xh = (_Float16*)(ws);
  _Float16* xl = (_Float16*)(ws + (32ull << 20));
  _Float16* wh = (_Float16*)(ws + (64ull << 20));
  _Float16* wl = (_Float16*)(ws + (72ull << 20));  // written, unused (R5)
  _Float16* wT = (_Float16*)(ws + (80ull << 20));
  float*    S  = (float*)   (ws + (88ull << 20));

  // gemm2 accumulates via atomics -> zero d_out first (graph-capture safe)
  hipMemsetAsync(d_out, 0, (size_t)M_ROWS * D_MODEL * sizeof(float), stream);

  hipLaunchKernelGGL(rmsnorm_split_kernel, dim3(MB_X + MB_W), dim3(256), 0,
                     stream, x, xh, xl, w, wh, wl);
  hipLaunchKernelGGL(transpose_kernel, dim3(D_MODEL / 32, D_FF / 32), dim3(256),
                     0, stream, w, wT);

  for (int c = 0; c < M_ROWS / MC; c++) {
    const long ro = (long)c * MC;
    hipLaunchKernelGGL(gemm1_kernel, dim3(D_FF / 256, MC / 128), dim3(256), 0,
                       stream, xh + ro * D_MODEL, xl + ro * D_MODEL, wh, S);
    hipLaunchKernelGGL(softmax_kernel, dim3(MC), dim3(256), 0, stream, S);
    hipLaunchKernelGGL(gemm2_kernel, dim3(D_MODEL / 128, MC / 128, 2),
                       dim3(256), 0, stream, (const _Float16*)S, wT,
                       out + ro * D_MODEL);
  }
}